// Round 9
// baseline (525.346 us; speedup 1.0000x reference)
//
#include <hip/hip_runtime.h>
#include <hip/hip_bf16.h>

// 3-layer GCN: per layer  out = relu(dinv .* segsum(dinv .* (X@W)) + b)
// fp16 pipeline: GEMMs via mfma_f32_16x16x32_f16 (f32 accum).
//  - "Copy-shaped" GEMM: one wave = 16 rows x 32 cols, ALL A-loads issued
//    upfront (MLP~16), B-frags from L1-hot Wt, zero LDS/barriers, 25k waves
//    (r6/r7/r8: three different staged GEMMs all ~64-79us, MfmaUtil ~3%,
//    HBM ~1TB/s -> outstanding-load-limited, not structure-limited).
// CSR build = deterministic two-level counting sort, zero global atomics
// (r5: few shared global cursors serialize at ~350ns/atomic).

#define NNODES 100000
#define NB 391          // buckets of 256 nodes: ceil(100000/256)
#define PB 2048         // edges per partition block
#define BCAP 12288      // per-bucket LDS sort capacity (mean 4096, sd ~64)

typedef _Float16 half8  __attribute__((ext_vector_type(8)));
typedef _Float16 half4v __attribute__((ext_vector_type(4)));
typedef _Float16 half2v __attribute__((ext_vector_type(2)));
typedef float    floatx4 __attribute__((ext_vector_type(4)));

static __device__ __forceinline__ floatx4 h2f4(half4v v) {
    return (floatx4){(float)v.x, (float)v.y, (float)v.z, (float)v.w};
}

// ---------------- CSR build: deterministic partition ----------------
__global__ __launch_bounds__(256) void blockhist_k(const int* __restrict__ dst,
                                                   int* __restrict__ H, int e) {
    __shared__ int h[NB];
    for (int q = threadIdx.x; q < NB; q += 256) h[q] = 0;
    __syncthreads();
    int base = blockIdx.x * PB;
    int lim = e - base; if (lim > PB) lim = PB;
    for (int i = threadIdx.x; i < lim; i += 256)
        atomicAdd(&h[dst[base + i] >> 8], 1);
    __syncthreads();
    for (int q = threadIdx.x; q < NB; q += 256)
        H[(size_t)blockIdx.x * NB + q] = h[q];
}

__global__ __launch_bounds__(256) void bucketscan_k(const int* __restrict__ H,
                                                    int* __restrict__ O,
                                                    int* __restrict__ T, int npb) {
    __shared__ int lds[256];
    int b = blockIdx.x, t = threadIdx.x;
    int running = 0;
    for (int c0 = 0; c0 < npb; c0 += 256) {
        int idx = c0 + t;
        int v = (idx < npb) ? H[(size_t)idx * NB + b] : 0;
        lds[t] = v;
        __syncthreads();
        #pragma unroll
        for (int off = 1; off < 256; off <<= 1) {
            int u = (t >= off) ? lds[t - off] : 0;
            __syncthreads();
            lds[t] += u;
            __syncthreads();
        }
        int excl = lds[t] - v + running;
        if (idx < npb) O[(size_t)idx * NB + b] = excl;
        running += lds[255];
        __syncthreads();
    }
    if (t == 0) T[b] = running;
}

__global__ __launch_bounds__(512) void scanT_k(const int* __restrict__ T,
                                               int* __restrict__ bbase, int e) {
    __shared__ int lds[512];
    int t = threadIdx.x;
    int v = (t < NB) ? T[t] : 0;
    lds[t] = v;
    __syncthreads();
    #pragma unroll
    for (int off = 1; off < 512; off <<= 1) {
        int u = (t >= off) ? lds[t - off] : 0;
        __syncthreads();
        lds[t] += u;
        __syncthreads();
    }
    if (t < NB) bbase[t] = lds[t] - v;
    if (t == 0) bbase[NB] = e;
}

__global__ __launch_bounds__(256) void scatter_k(const int* __restrict__ src,
                                                 const int* __restrict__ dst,
                                                 const int* __restrict__ O,
                                                 const int* __restrict__ bbase,
                                                 unsigned* __restrict__ binned, int e) {
    __shared__ int cur[NB];
    for (int q = threadIdx.x; q < NB; q += 256)
        cur[q] = bbase[q] + O[(size_t)blockIdx.x * NB + q];
    __syncthreads();
    int base = blockIdx.x * PB;
    int lim = e - base; if (lim > PB) lim = PB;
    for (int i = threadIdx.x; i < lim; i += 256) {
        int d = dst[base + i];
        int s = src[base + i];
        int p = atomicAdd(&cur[d >> 8], 1);
        binned[p] = ((unsigned)(d & 255) << 17) | (unsigned)s;
    }
}

__global__ __launch_bounds__(256) void bucket_fill_k(
    const unsigned* __restrict__ binned, const int* __restrict__ bbase,
    int* __restrict__ rowptr, int* __restrict__ eidx,
    float* __restrict__ dinv, int n, int e) {
    __shared__ int cnt[256];
    __shared__ int cur[256];
    __shared__ int lds[256];
    __shared__ int sbuf[BCAP];
    int b = blockIdx.x, t = threadIdx.x;
    int beg = bbase[b], end = bbase[b + 1];
    int m = end - beg;
    cnt[t] = 0;
    __syncthreads();
    for (int q = t; q < m; q += 256) {
        unsigned r = binned[beg + q];
        atomicAdd(&cnt[r >> 17], 1);
    }
    __syncthreads();
    int v = cnt[t];
    lds[t] = v;
    __syncthreads();
    #pragma unroll
    for (int off = 1; off < 256; off <<= 1) {
        int u = (t >= off) ? lds[t - off] : 0;
        __syncthreads();
        lds[t] += u;
        __syncthreads();
    }
    int excl = lds[t] - v;
    int node = b * 256 + t;
    if (node < n) {
        rowptr[node] = beg + excl;
        dinv[node] = rsqrtf(1.0f + (float)v);
    }
    if (b == NB - 1 && t == 0) rowptr[n] = e;
    cur[t] = excl;
    __syncthreads();
    for (int q = t; q < m; q += 256) {
        unsigned r = binned[beg + q];
        int p = atomicAdd(&cur[r >> 17], 1);
        if (p < BCAP) sbuf[p] = (int)(r & 0x1FFFFu);
    }
    __syncthreads();
    for (int q = t; q < m; q += 256) eidx[beg + q] = sbuf[q];
}

// ---------------- W transpose+cast (once): Wt[n][k] fp16 ----------------
__global__ __launch_bounds__(256) void castWt_k(
    const float* __restrict__ W1, const float* __restrict__ W2,
    const float* __restrict__ W3, _Float16* __restrict__ Wt1,
    _Float16* __restrict__ Wt2, _Float16* __restrict__ Wt3) {
    int i = blockIdx.x * 256 + threadIdx.x;
    if (i < 128 * 256) {             // Wt1[128][256] <- W1[256][128]
        int nn = i >> 8, k = i & 255;
        Wt1[i] = (_Float16)W1[k * 128 + nn];
    }
    if (i < 128 * 128) {             // Wt2[128][128] <- W2[128][128]
        int nn = i >> 7, k = i & 127;
        Wt2[i] = (_Float16)W2[k * 128 + nn];
    }
    if (i < 64 * 128) {              // Wt3[64][128] <- W3[128][64]
        int nn = i >> 7, k = i & 127;
        Wt3[i] = (_Float16)W3[k * 64 + nn];
    }
}

// ----- copy-shaped GEMM: wave = 16 rows x (NCT*16) cols, K fully resident -----
// block = 4 waves = 16 rows x FOUT cols; all A-loads upfront (independent),
// B-frags from global Wt (L1-hot, shared by all blocks); no LDS, no barriers.
template<typename TA, int FIN, int FOUT>
__global__ __launch_bounds__(256, 2) void gemm_wave_k(
    const TA* __restrict__ X, const _Float16* __restrict__ Wt,
    const float* __restrict__ dinv, _Float16* __restrict__ G, int n)
{
    constexpr int NKC = FIN / 32;        // k-chunks per row
    constexpr int NCT = FOUT / 64;       // col-tiles per wave (2 or 1)
    const int wave = threadIdx.x >> 6;
    const int lane = threadIdx.x & 63;
    const int mrow = lane & 15;
    const int kq   = (lane >> 4) * 8;
    const int m0   = blockIdx.x * 16;

    int r = m0 + mrow; if (r > n - 1) r = n - 1;   // junk rows never stored

    // ---- all A-loads issued upfront (max outstanding) ----
    half8 af[NKC];
    if constexpr (sizeof(TA) == 4) {
        const float* xp = (const float*)X + (size_t)r * FIN + kq;
        float4 t[2 * NKC];
        #pragma unroll
        for (int kc = 0; kc < NKC; ++kc) {
            t[2 * kc]     = *(const float4*)(xp + kc * 32);
            t[2 * kc + 1] = *(const float4*)(xp + kc * 32 + 4);
        }
        #pragma unroll
        for (int kc = 0; kc < NKC; ++kc) {
            float4 u0 = t[2 * kc], u1 = t[2 * kc + 1];
            af[kc] = (half8){(_Float16)u0.x, (_Float16)u0.y, (_Float16)u0.z, (_Float16)u0.w,
                             (_Float16)u1.x, (_Float16)u1.y, (_Float16)u1.z, (_Float16)u1.w};
        }
    } else {
        const _Float16* xp = (const _Float16*)X + (size_t)r * FIN + kq;
        #pragma unroll
        for (int kc = 0; kc < NKC; ++kc)
            af[kc] = *(const half8*)(xp + kc * 32);
    }

    // ---- B fragments (L1/L2-hot) ----
    half8 bf[NCT][NKC];
    #pragma unroll
    for (int ct = 0; ct < NCT; ++ct) {
        const _Float16* wp = Wt + (size_t)((wave * NCT + ct) * 16 + mrow) * FIN + kq;
        #pragma unroll
        for (int kc = 0; kc < NKC; ++kc)
            bf[ct][kc] = *(const half8*)(wp + kc * 32);
    }

    // ---- MFMA burst ----
    floatx4 acc[NCT];
    #pragma unroll
    for (int ct = 0; ct < NCT; ++ct) acc[ct] = (floatx4){0.f, 0.f, 0.f, 0.f};
    #pragma unroll
    for (int kc = 0; kc < NKC; ++kc)
        #pragma unroll
        for (int ct = 0; ct < NCT; ++ct)
            acc[ct] = __builtin_amdgcn_mfma_f32_16x16x32_f16(af[kc], bf[ct][kc], acc[ct], 0, 0, 0);

    // D layout: col = lane&15, row = (lane>>4)*4 + reg  [m89/m91 verified]
    #pragma unroll
    for (int reg = 0; reg < 4; ++reg) {
        int rr = m0 + (lane >> 4) * 4 + reg;
        if (rr < n) {
            float s = dinv[rr];
            #pragma unroll
            for (int ct = 0; ct < NCT; ++ct)
                G[(size_t)rr * FOUT + (wave * NCT + ct) * 16 + mrow] =
                    (_Float16)(acc[ct][reg] * s);
        }
    }
}

// -------- CSR gather segsum, F=128: half-wave, 4 rows in flight per half --------
template<bool RELU, typename OutT>
__global__ __launch_bounds__(256) void gather128_k(
    const _Float16* __restrict__ g, const int* __restrict__ rowptr,
    const int* __restrict__ eidx, const float* __restrict__ dinv,
    const float* __restrict__ bias, OutT* __restrict__ out, int n)
{
    int wave = threadIdx.x >> 6;
    int lane = threadIdx.x & 63;
    int half = lane >> 5;
    int hl   = lane & 31;
    int node = blockIdx.x * 4 + wave;
    if (node >= n) return;

    int beg = rowptr[node];
    int end = rowptr[node + 1];

    const half4v* g4 = (const half4v*)g;     // row stride = 32 half4
    floatx4 aA = {0.f,0.f,0.f,0.f}, aB = aA, aC = aA, aD = aA;
    if (half == 0) aA = h2f4(g4[(size_t)node * 32 + hl]);   // self loop

    for (int j0 = beg; j0 < end; j0 += 64) {
        int m = end - j0; if (m > 64) m = 64;
        int id = (lane < m) ? eidx[j0 + lane] : 0;
        int t = 0;
        for (; t + 7 < m; t += 8) {
            int i0 = __shfl(id, t + half);
            int i1 = __shfl(id, t + 2 + half);
            int i2 = __shfl(id, t + 4 + half);
            int i3 = __shfl(id, t + 6 + half);
            half4v v0 = g4[(size_t)i0 * 32 + hl];
            half4v v1 = g4[(size_t)i1 * 32 + hl];
            half4v v2 = g4[(size_t)i2 * 32 + hl];
            half4v v3 = g4[(size_t)i3 * 32 + hl];
            aA += h2f4(v0); aB += h2f4(v1); aC += h2f4(v2); aD += h2f4(v3);
        }
        for (; t + 1 < m; t += 2) {
            int i0 = __shfl(id, t + half);
            aA += h2f4(g4[(size_t)i0 * 32 + hl]);
        }
        if (t < m) {
            int i0 = __shfl(id, t);
            if (half == 0) aA += h2f4(g4[(size_t)i0 * 32 + hl]);
        }
    }
    aA += aB; aC += aD; aA += aC;
    aA.x += __shfl_down(aA.x, 32);
    aA.y += __shfl_down(aA.y, 32);
    aA.z += __shfl_down(aA.z, 32);
    aA.w += __shfl_down(aA.w, 32);

    if (half == 0) {
        float sc = dinv[node];
        float4 bb = *(const float4*)(bias + 4 * hl);
        float o0 = fmaf(aA.x, sc, bb.x);
        float o1 = fmaf(aA.y, sc, bb.y);
        float o2 = fmaf(aA.z, sc, bb.z);
        float o3 = fmaf(aA.w, sc, bb.w);
        if (RELU) {
            o0 = fmaxf(o0, 0.f); o1 = fmaxf(o1, 0.f);
            o2 = fmaxf(o2, 0.f); o3 = fmaxf(o3, 0.f);
        }
        if constexpr (sizeof(OutT) == 2) {
            ((half4v*)out)[(size_t)node * 32 + hl] =
                (half4v){(_Float16)o0, (_Float16)o1, (_Float16)o2, (_Float16)o3};
        } else {
            *(float4*)((float*)out + (size_t)node * 128 + 4 * hl) =
                make_float4(o0, o1, o2, o3);
        }
    }
}

// -------- F=64 variant: half-wave, half2 loads, 4 rows in flight per half --------
template<bool RELU>
__global__ __launch_bounds__(256) void gather64_k(
    const _Float16* __restrict__ g, const int* __restrict__ rowptr,
    const int* __restrict__ eidx, const float* __restrict__ dinv,
    const float* __restrict__ bias, float* __restrict__ out, int n)
{
    int wave = threadIdx.x >> 6;
    int lane = threadIdx.x & 63;
    int half = lane >> 5;
    int hl   = lane & 31;
    int node = blockIdx.x * 4 + wave;
    if (node >= n) return;

    int beg = rowptr[node];
    int end = rowptr[node + 1];

    const half2v* g2 = (const half2v*)g;     // row stride = 32 half2
    float ax=0.f, ay=0.f, bx=0.f, by=0.f, cx=0.f, cy=0.f, dx=0.f, dy=0.f;
    if (half == 0) {
        half2v v = g2[(size_t)node * 32 + hl];
        ax = (float)v.x; ay = (float)v.y;
    }

    for (int j0 = beg; j0 < end; j0 += 64) {
        int m = end - j0; if (m > 64) m = 64;
        int id = (lane < m) ? eidx[j0 + lane] : 0;
        int t = 0;
        for (; t + 7 < m; t += 8) {
            int i0 = __shfl(id, t + half);
            int i1 = __shfl(id, t + 2 + half);
            int i2 = __shfl(id, t + 4 + half);
            int i3 = __shfl(id, t + 6 + half);
            half2v v0 = g2[(size_t)i0 * 32 + hl];
            half2v v1 = g2[(size_t)i1 * 32 + hl];
            half2v v2 = g2[(size_t)i2 * 32 + hl];
            half2v v3 = g2[(size_t)i3 * 32 + hl];
            ax += (float)v0.x; ay += (float)v0.y;
            bx += (float)v1.x; by += (float)v1.y;
            cx += (float)v2.x; cy += (float)v2.y;
            dx += (float)v3.x; dy += (float)v3.y;
        }
        for (; t + 1 < m; t += 2) {
            int i0 = __shfl(id, t + half);
            half2v v0 = g2[(size_t)i0 * 32 + hl];
            ax += (float)v0.x; ay += (float)v0.y;
        }
        if (t < m) {
            int i0 = __shfl(id, t);
            if (half == 0) {
                half2v v0 = g2[(size_t)i0 * 32 + hl];
                ax += (float)v0.x; ay += (float)v0.y;
            }
        }
    }
    ax += bx + cx + dx; ay += by + cy + dy;
    ax += __shfl_down(ax, 32);
    ay += __shfl_down(ay, 32);

    if (half == 0) {
        float sc = dinv[node];
        float2 bb = *(const float2*)(bias + 2 * hl);
        float ox = fmaf(ax, sc, bb.x);
        float oy = fmaf(ay, sc, bb.y);
        if (RELU) { ox = fmaxf(ox, 0.f); oy = fmaxf(oy, 0.f); }
        *(float2*)(out + (size_t)node * 64 + 2 * hl) = make_float2(ox, oy);
    }
}

extern "C" void kernel_launch(void* const* d_in, const int* in_sizes, int n_in,
                              void* d_out, int out_size, void* d_ws, size_t ws_size,
                              hipStream_t stream) {
    const float* x  = (const float*)d_in[0];
    const int*   ei = (const int*)d_in[1];     // [2, E] int32
    const float* W1 = (const float*)d_in[2];
    const float* b1 = (const float*)d_in[3];
    const float* W2 = (const float*)d_in[4];
    const float* b2 = (const float*)d_in[5];
    const float* W3 = (const float*)d_in[6];
    const float* b3 = (const float*)d_in[7];
    float* out = (float*)d_out;

    const int N = NNODES;
    const int E = in_sizes[1] / 2;
    const int* srcI = ei;
    const int* dstI = ei + E;

    const int npb = (E + PB - 1) / PB;

    char* ws = (char*)d_ws;
    size_t p = 0;
    auto alloc = [&](size_t bytes) { void* r = ws + p; p = (p + bytes + 255) & ~(size_t)255; return r; };
    float*     dinv   = (float*)    alloc((size_t)N * 4);
    int*       rowptr = (int*)      alloc((size_t)(N + 1) * 4);
    int*       bbase  = (int*)      alloc((size_t)(NB + 1) * 4);
    int*       T      = (int*)      alloc((size_t)NB * 4);
    int*       H      = (int*)      alloc((size_t)npb * NB * 4);
    int*       O      = (int*)      alloc((size_t)npb * NB * 4);
    unsigned*  binned = (unsigned*) alloc((size_t)E * 4);
    int*       eidx   = (int*)      alloc((size_t)E * 4);
    _Float16*  Wt1    = (_Float16*) alloc((size_t)128 * 256 * 2);
    _Float16*  Wt2    = (_Float16*) alloc((size_t)128 * 128 * 2);
    _Float16*  Wt3    = (_Float16*) alloc((size_t)64 * 128 * 2);
    _Float16*  A      = (_Float16*) alloc((size_t)N * 128 * 2);
    _Float16*  Ch     = (_Float16*) alloc((size_t)N * 128 * 2);

    const int nb_node4 = (N + 3) / 4;
    const int nb_gemm = (N + 15) / 16;     // 6250 blocks, 16 rows each

    // ---- CSR build + weight prep ----
    blockhist_k<<<npb, 256, 0, stream>>>(dstI, H, E);
    castWt_k<<<128, 256, 0, stream>>>(W1, W2, W3, Wt1, Wt2, Wt3);
    bucketscan_k<<<NB, 256, 0, stream>>>(H, O, T, npb);
    scanT_k<<<1, 512, 0, stream>>>(T, bbase, E);
    scatter_k<<<npb, 256, 0, stream>>>(srcI, dstI, O, bbase, binned, E);
    bucket_fill_k<<<NB, 256, 0, stream>>>(binned, bbase, rowptr, eidx, dinv, N, E);

    // ---- layer 1: FEAT=256 -> HID=128 ----
    gemm_wave_k<float, 256, 128><<<nb_gemm, 256, 0, stream>>>(x, Wt1, dinv, A, N);
    gather128_k<true, _Float16><<<nb_node4, 256, 0, stream>>>(A, rowptr, eidx, dinv, b1, Ch, N);

    // ---- layer 2: HID=128 -> HID=128 ----
    gemm_wave_k<_Float16, 128, 128><<<nb_gemm, 256, 0, stream>>>(Ch, Wt2, dinv, A, N);
    gather128_k<true, _Float16><<<nb_node4, 256, 0, stream>>>(A, rowptr, eidx, dinv, b2, Ch, N);

    // ---- layer 3: HID=128 -> OUT=64 ----
    gemm_wave_k<_Float16, 128, 64><<<nb_gemm, 256, 0, stream>>>(Ch, Wt3, dinv, A, N);
    gather64_k<false><<<nb_node4, 256, 0, stream>>>(A, rowptr, eidx, dinv, b3, out, N);
}

// Round 10
// 444.287 us; speedup vs baseline: 1.1824x; 1.1824x over previous
//
#include <hip/hip_runtime.h>
#include <hip/hip_bf16.h>

// 3-layer GCN: per layer  out = relu(dinv .* segsum(dinv .* (X@W)) + b)
// fp16 pipeline: GEMMs via mfma_f32_16x16x32_f16 (f32 accum).
//  - GEMM: waves own DISJOINT 16-row strips x all FOUT cols (A read exactly
//    once — r8/r9's 4x A amplification removed); B staged to LDS ONCE per
//    block (single barrier — r6/r7's per-kc barrier serialization removed);
//    W pre-stored in MFMA fragment order -> memcpy staging + conflict-free
//    stride-1 ds_read_b128.
// CSR build = deterministic two-level counting sort, zero global atomics
// (r5: few shared global cursors serialize at ~350ns/atomic).

#define NNODES 100000
#define NB 391          // buckets of 256 nodes: ceil(100000/256)
#define PB 2048         // edges per partition block
#define BCAP 12288      // per-bucket LDS sort capacity (mean 4096, sd ~64)

typedef _Float16 half8  __attribute__((ext_vector_type(8)));
typedef _Float16 half4v __attribute__((ext_vector_type(4)));
typedef _Float16 half2v __attribute__((ext_vector_type(2)));
typedef float    floatx4 __attribute__((ext_vector_type(4)));

static __device__ __forceinline__ floatx4 h2f4(half4v v) {
    return (floatx4){(float)v.x, (float)v.y, (float)v.z, (float)v.w};
}

// ---------------- CSR build: deterministic partition ----------------
__global__ __launch_bounds__(256) void blockhist_k(const int* __restrict__ dst,
                                                   int* __restrict__ H, int e) {
    __shared__ int h[NB];
    for (int q = threadIdx.x; q < NB; q += 256) h[q] = 0;
    __syncthreads();
    int base = blockIdx.x * PB;
    int lim = e - base; if (lim > PB) lim = PB;
    for (int i = threadIdx.x; i < lim; i += 256)
        atomicAdd(&h[dst[base + i] >> 8], 1);
    __syncthreads();
    for (int q = threadIdx.x; q < NB; q += 256)
        H[(size_t)blockIdx.x * NB + q] = h[q];
}

__global__ __launch_bounds__(256) void bucketscan_k(const int* __restrict__ H,
                                                    int* __restrict__ O,
                                                    int* __restrict__ T, int npb) {
    __shared__ int lds[256];
    int b = blockIdx.x, t = threadIdx.x;
    int running = 0;
    for (int c0 = 0; c0 < npb; c0 += 256) {
        int idx = c0 + t;
        int v = (idx < npb) ? H[(size_t)idx * NB + b] : 0;
        lds[t] = v;
        __syncthreads();
        #pragma unroll
        for (int off = 1; off < 256; off <<= 1) {
            int u = (t >= off) ? lds[t - off] : 0;
            __syncthreads();
            lds[t] += u;
            __syncthreads();
        }
        int excl = lds[t] - v + running;
        if (idx < npb) O[(size_t)idx * NB + b] = excl;
        running += lds[255];
        __syncthreads();
    }
    if (t == 0) T[b] = running;
}

__global__ __launch_bounds__(512) void scanT_k(const int* __restrict__ T,
                                               int* __restrict__ bbase, int e) {
    __shared__ int lds[512];
    int t = threadIdx.x;
    int v = (t < NB) ? T[t] : 0;
    lds[t] = v;
    __syncthreads();
    #pragma unroll
    for (int off = 1; off < 512; off <<= 1) {
        int u = (t >= off) ? lds[t - off] : 0;
        __syncthreads();
        lds[t] += u;
        __syncthreads();
    }
    if (t < NB) bbase[t] = lds[t] - v;
    if (t == 0) bbase[NB] = e;
}

__global__ __launch_bounds__(256) void scatter_k(const int* __restrict__ src,
                                                 const int* __restrict__ dst,
                                                 const int* __restrict__ O,
                                                 const int* __restrict__ bbase,
                                                 unsigned* __restrict__ binned, int e) {
    __shared__ int cur[NB];
    for (int q = threadIdx.x; q < NB; q += 256)
        cur[q] = bbase[q] + O[(size_t)blockIdx.x * NB + q];
    __syncthreads();
    int base = blockIdx.x * PB;
    int lim = e - base; if (lim > PB) lim = PB;
    for (int i = threadIdx.x; i < lim; i += 256) {
        int d = dst[base + i];
        int s = src[base + i];
        int p = atomicAdd(&cur[d >> 8], 1);
        binned[p] = ((unsigned)(d & 255) << 17) | (unsigned)s;
    }
}

__global__ __launch_bounds__(256) void bucket_fill_k(
    const unsigned* __restrict__ binned, const int* __restrict__ bbase,
    int* __restrict__ rowptr, int* __restrict__ eidx,
    float* __restrict__ dinv, int n, int e) {
    __shared__ int cnt[256];
    __shared__ int cur[256];
    __shared__ int lds[256];
    __shared__ int sbuf[BCAP];
    int b = blockIdx.x, t = threadIdx.x;
    int beg = bbase[b], end = bbase[b + 1];
    int m = end - beg;
    cnt[t] = 0;
    __syncthreads();
    for (int q = t; q < m; q += 256) {
        unsigned r = binned[beg + q];
        atomicAdd(&cnt[r >> 17], 1);
    }
    __syncthreads();
    int v = cnt[t];
    lds[t] = v;
    __syncthreads();
    #pragma unroll
    for (int off = 1; off < 256; off <<= 1) {
        int u = (t >= off) ? lds[t - off] : 0;
        __syncthreads();
        lds[t] += u;
        __syncthreads();
    }
    int excl = lds[t] - v;
    int node = b * 256 + t;
    if (node < n) {
        rowptr[node] = beg + excl;
        dinv[node] = rsqrtf(1.0f + (float)v);
    }
    if (b == NB - 1 && t == 0) rowptr[n] = e;
    cur[t] = excl;
    __syncthreads();
    for (int q = t; q < m; q += 256) {
        unsigned r = binned[beg + q];
        int p = atomicAdd(&cur[r >> 17], 1);
        if (p < BCAP) sbuf[p] = (int)(r & 0x1FFFFu);
    }
    __syncthreads();
    for (int q = t; q < m; q += 256) eidx[beg + q] = sbuf[q];
}

// ------- W cast to fp16 in MFMA fragment order (once) -------
// frag idx for element (k,n): ct=n>>4, mrow=n&15, kc=k>>5, hi=(k&31)>>3, j=k&7
// idx = ((ct*NKC+kc)*64 + hi*16+mrow)*8 + j   (NKC = FIN/32)
static __device__ __forceinline__ void cast_frag(
    const float* __restrict__ W, _Float16* __restrict__ Wf,
    int FIN, int FOUT, int i) {
    int k = i / FOUT, n = i % FOUT;
    int ct = n >> 4, mrow = n & 15;
    int kc = k >> 5, hi = (k & 31) >> 3, j = k & 7;
    int NKC = FIN / 32;
    int idx = ((ct * NKC + kc) * 64 + hi * 16 + mrow) * 8 + j;
    Wf[idx] = (_Float16)W[(size_t)k * FOUT + n];
}

__global__ __launch_bounds__(256) void castW_k(
    const float* __restrict__ W1, const float* __restrict__ W2,
    const float* __restrict__ W3, _Float16* __restrict__ Wf1,
    _Float16* __restrict__ Wf2, _Float16* __restrict__ Wf3) {
    int i = blockIdx.x * 256 + threadIdx.x;
    if (i < 256 * 128) cast_frag(W1, Wf1, 256, 128, i);
    if (i < 128 * 128) cast_frag(W2, Wf2, 128, 128, i);
    if (i < 128 * 64)  cast_frag(W3, Wf3, 128, 64, i);
}

// ------- GEMM: G(fp16) = (X@W)*dinv[row]; disjoint rows/wave, LDS-B once -------
// block = 4 waves x 16 rows = 64 rows, all FOUT cols per wave.
// B (fragment-ordered) staged to LDS once (memcpy); one barrier total.
template<typename TA, int FIN, int FOUT>
__global__ __launch_bounds__(256, 2) void gemm_ldsB_k(
    const TA* __restrict__ X, const _Float16* __restrict__ Wf,
    const float* __restrict__ dinv, _Float16* __restrict__ G, int n)
{
    constexpr int NKC = FIN / 32;        // k-chunks
    constexpr int NCT = FOUT / 16;       // col tiles (all owned by each wave)
    __shared__ _Float16 wS[FOUT * FIN];  // 64/32/16 KB

    const int tid  = threadIdx.x;
    const int wave = tid >> 6;
    const int lane = tid & 63;
    const int mrow = lane & 15;
    const int kq   = (lane >> 4) * 8;

    // stage fragment-ordered W -> LDS (contiguous memcpy)
    {
        const half8* s = (const half8*)Wf;
        half8* d = (half8*)wS;
        constexpr int TOT8 = FOUT * FIN / 8;
        #pragma unroll
        for (int i = tid; i < TOT8; i += 256) d[i] = s[i];
    }

    int r = blockIdx.x * 64 + wave * 16 + mrow;
    if (r > n - 1) r = n - 1;            // junk rows never stored

    // all A-loads upfront (independent, overlap the staging + barrier)
    half8 af[NKC];
    if constexpr (sizeof(TA) == 4) {
        const float* xp = (const float*)X + (size_t)r * FIN + kq;
        float4 t0[NKC], t1[NKC];
        #pragma unroll
        for (int kc = 0; kc < NKC; ++kc) {
            t0[kc] = *(const float4*)(xp + kc * 32);
            t1[kc] = *(const float4*)(xp + kc * 32 + 4);
        }
        #pragma unroll
        for (int kc = 0; kc < NKC; ++kc) {
            float4 u0 = t0[kc], u1 = t1[kc];
            af[kc] = (half8){(_Float16)u0.x, (_Float16)u0.y, (_Float16)u0.z, (_Float16)u0.w,
                             (_Float16)u1.x, (_Float16)u1.y, (_Float16)u1.z, (_Float16)u1.w};
        }
    } else {
        const _Float16* xp = (const _Float16*)X + (size_t)r * FIN + kq;
        #pragma unroll
        for (int kc = 0; kc < NKC; ++kc)
            af[kc] = *(const half8*)(xp + kc * 32);
    }

    __syncthreads();                     // the only barrier

    floatx4 acc[NCT];
    #pragma unroll
    for (int ct = 0; ct < NCT; ++ct) acc[ct] = (floatx4){0.f, 0.f, 0.f, 0.f};

    #pragma unroll
    for (int kc = 0; kc < NKC; ++kc) {
        #pragma unroll
        for (int ct = 0; ct < NCT; ++ct) {
            // stride-1 ds_read_b128: addr = ((ct*NKC+kc)*64 + lane)*16B
            half8 bf = *(const half8*)&wS[(((ct * NKC) + kc) * 64 + lane) * 8];
            acc[ct] = __builtin_amdgcn_mfma_f32_16x16x32_f16(af[kc], bf, acc[ct], 0, 0, 0);
        }
    }

    // D layout: col = lane&15, row = (lane>>4)*4 + reg  [m89/m91 verified]
    int rbase = blockIdx.x * 64 + wave * 16 + (lane >> 4) * 4;
    #pragma unroll
    for (int reg = 0; reg < 4; ++reg) {
        int rr = rbase + reg;
        if (rr < n) {
            float s = dinv[rr];
            #pragma unroll
            for (int ct = 0; ct < NCT; ++ct)
                G[(size_t)rr * FOUT + ct * 16 + mrow] = (_Float16)(acc[ct][reg] * s);
        }
    }
}

// -------- CSR gather segsum, F=128: half-wave, 4 rows in flight per half --------
template<bool RELU, typename OutT>
__global__ __launch_bounds__(256) void gather128_k(
    const _Float16* __restrict__ g, const int* __restrict__ rowptr,
    const int* __restrict__ eidx, const float* __restrict__ dinv,
    const float* __restrict__ bias, OutT* __restrict__ out, int n)
{
    int wave = threadIdx.x >> 6;
    int lane = threadIdx.x & 63;
    int half = lane >> 5;
    int hl   = lane & 31;
    int node = blockIdx.x * 4 + wave;
    if (node >= n) return;

    int beg = rowptr[node];
    int end = rowptr[node + 1];

    const half4v* g4 = (const half4v*)g;     // row stride = 32 half4
    floatx4 aA = {0.f,0.f,0.f,0.f}, aB = aA, aC = aA, aD = aA;
    if (half == 0) aA = h2f4(g4[(size_t)node * 32 + hl]);   // self loop

    for (int j0 = beg; j0 < end; j0 += 64) {
        int m = end - j0; if (m > 64) m = 64;
        int id = (lane < m) ? eidx[j0 + lane] : 0;
        int t = 0;
        for (; t + 7 < m; t += 8) {
            int i0 = __shfl(id, t + half);
            int i1 = __shfl(id, t + 2 + half);
            int i2 = __shfl(id, t + 4 + half);
            int i3 = __shfl(id, t + 6 + half);
            half4v v0 = g4[(size_t)i0 * 32 + hl];
            half4v v1 = g4[(size_t)i1 * 32 + hl];
            half4v v2 = g4[(size_t)i2 * 32 + hl];
            half4v v3 = g4[(size_t)i3 * 32 + hl];
            aA += h2f4(v0); aB += h2f4(v1); aC += h2f4(v2); aD += h2f4(v3);
        }
        for (; t + 1 < m; t += 2) {
            int i0 = __shfl(id, t + half);
            aA += h2f4(g4[(size_t)i0 * 32 + hl]);
        }
        if (t < m) {
            int i0 = __shfl(id, t);
            if (half == 0) aA += h2f4(g4[(size_t)i0 * 32 + hl]);
        }
    }
    aA += aB; aC += aD; aA += aC;
    aA.x += __shfl_down(aA.x, 32);
    aA.y += __shfl_down(aA.y, 32);
    aA.z += __shfl_down(aA.z, 32);
    aA.w += __shfl_down(aA.w, 32);

    if (half == 0) {
        float sc = dinv[node];
        float4 bb = *(const float4*)(bias + 4 * hl);
        float o0 = fmaf(aA.x, sc, bb.x);
        float o1 = fmaf(aA.y, sc, bb.y);
        float o2 = fmaf(aA.z, sc, bb.z);
        float o3 = fmaf(aA.w, sc, bb.w);
        if (RELU) {
            o0 = fmaxf(o0, 0.f); o1 = fmaxf(o1, 0.f);
            o2 = fmaxf(o2, 0.f); o3 = fmaxf(o3, 0.f);
        }
        if constexpr (sizeof(OutT) == 2) {
            ((half4v*)out)[(size_t)node * 32 + hl] =
                (half4v){(_Float16)o0, (_Float16)o1, (_Float16)o2, (_Float16)o3};
        } else {
            *(float4*)((float*)out + (size_t)node * 128 + 4 * hl) =
                make_float4(o0, o1, o2, o3);
        }
    }
}

// -------- F=64 variant: half-wave, half2 loads, 4 rows in flight per half --------
template<bool RELU>
__global__ __launch_bounds__(256) void gather64_k(
    const _Float16* __restrict__ g, const int* __restrict__ rowptr,
    const int* __restrict__ eidx, const float* __restrict__ dinv,
    const float* __restrict__ bias, float* __restrict__ out, int n)
{
    int wave = threadIdx.x >> 6;
    int lane = threadIdx.x & 63;
    int half = lane >> 5;
    int hl   = lane & 31;
    int node = blockIdx.x * 4 + wave;
    if (node >= n) return;

    int beg = rowptr[node];
    int end = rowptr[node + 1];

    const half2v* g2 = (const half2v*)g;     // row stride = 32 half2
    float ax=0.f, ay=0.f, bx=0.f, by=0.f, cx=0.f, cy=0.f, dx=0.f, dy=0.f;
    if (half == 0) {
        half2v v = g2[(size_t)node * 32 + hl];
        ax = (float)v.x; ay = (float)v.y;
    }

    for (int j0 = beg; j0 < end; j0 += 64) {
        int m = end - j0; if (m > 64) m = 64;
        int id = (lane < m) ? eidx[j0 + lane] : 0;
        int t = 0;
        for (; t + 7 < m; t += 8) {
            int i0 = __shfl(id, t + half);
            int i1 = __shfl(id, t + 2 + half);
            int i2 = __shfl(id, t + 4 + half);
            int i3 = __shfl(id, t + 6 + half);
            half2v v0 = g2[(size_t)i0 * 32 + hl];
            half2v v1 = g2[(size_t)i1 * 32 + hl];
            half2v v2 = g2[(size_t)i2 * 32 + hl];
            half2v v3 = g2[(size_t)i3 * 32 + hl];
            ax += (float)v0.x; ay += (float)v0.y;
            bx += (float)v1.x; by += (float)v1.y;
            cx += (float)v2.x; cy += (float)v2.y;
            dx += (float)v3.x; dy += (float)v3.y;
        }
        for (; t + 1 < m; t += 2) {
            int i0 = __shfl(id, t + half);
            half2v v0 = g2[(size_t)i0 * 32 + hl];
            ax += (float)v0.x; ay += (float)v0.y;
        }
        if (t < m) {
            int i0 = __shfl(id, t);
            if (half == 0) {
                half2v v0 = g2[(size_t)i0 * 32 + hl];
                ax += (float)v0.x; ay += (float)v0.y;
            }
        }
    }
    ax += bx + cx + dx; ay += by + cy + dy;
    ax += __shfl_down(ax, 32);
    ay += __shfl_down(ay, 32);

    if (half == 0) {
        float sc = dinv[node];
        float2 bb = *(const float2*)(bias + 2 * hl);
        float ox = fmaf(ax, sc, bb.x);
        float oy = fmaf(ay, sc, bb.y);
        if (RELU) { ox = fmaxf(ox, 0.f); oy = fmaxf(oy, 0.f); }
        *(float2*)(out + (size_t)node * 64 + 2 * hl) = make_float2(ox, oy);
    }
}

extern "C" void kernel_launch(void* const* d_in, const int* in_sizes, int n_in,
                              void* d_out, int out_size, void* d_ws, size_t ws_size,
                              hipStream_t stream) {
    const float* x  = (const float*)d_in[0];
    const int*   ei = (const int*)d_in[1];     // [2, E] int32
    const float* W1 = (const float*)d_in[2];
    const float* b1 = (const float*)d_in[3];
    const float* W2 = (const float*)d_in[4];
    const float* b2 = (const float*)d_in[5];
    const float* W3 = (const float*)d_in[6];
    const float* b3 = (const float*)d_in[7];
    float* out = (float*)d_out;

    const int N = NNODES;
    const int E = in_sizes[1] / 2;
    const int* srcI = ei;
    const int* dstI = ei + E;

    const int npb = (E + PB - 1) / PB;

    char* ws = (char*)d_ws;
    size_t p = 0;
    auto alloc = [&](size_t bytes) { void* r = ws + p; p = (p + bytes + 255) & ~(size_t)255; return r; };
    float*     dinv   = (float*)    alloc((size_t)N * 4);
    int*       rowptr = (int*)      alloc((size_t)(N + 1) * 4);
    int*       bbase  = (int*)      alloc((size_t)(NB + 1) * 4);
    int*       T      = (int*)      alloc((size_t)NB * 4);
    int*       H      = (int*)      alloc((size_t)npb * NB * 4);
    int*       O      = (int*)      alloc((size_t)npb * NB * 4);
    unsigned*  binned = (unsigned*) alloc((size_t)E * 4);
    int*       eidx   = (int*)      alloc((size_t)E * 4);
    _Float16*  Wf1    = (_Float16*) alloc((size_t)128 * 256 * 2);
    _Float16*  Wf2    = (_Float16*) alloc((size_t)128 * 128 * 2);
    _Float16*  Wf3    = (_Float16*) alloc((size_t)64 * 128 * 2);
    _Float16*  A      = (_Float16*) alloc((size_t)N * 128 * 2);
    _Float16*  Ch     = (_Float16*) alloc((size_t)N * 128 * 2);

    const int nb_node4 = (N + 3) / 4;
    const int nb_gemm = (N + 63) / 64;     // 1563 blocks, 64 rows each

    // ---- CSR build + weight prep ----
    blockhist_k<<<npb, 256, 0, stream>>>(dstI, H, E);
    castW_k<<<128, 256, 0, stream>>>(W1, W2, W3, Wf1, Wf2, Wf3);
    bucketscan_k<<<NB, 256, 0, stream>>>(H, O, T, npb);
    scanT_k<<<1, 512, 0, stream>>>(T, bbase, E);
    scatter_k<<<npb, 256, 0, stream>>>(srcI, dstI, O, bbase, binned, E);
    bucket_fill_k<<<NB, 256, 0, stream>>>(binned, bbase, rowptr, eidx, dinv, N, E);

    // ---- layer 1: FEAT=256 -> HID=128 ----
    gemm_ldsB_k<float, 256, 128><<<nb_gemm, 256, 0, stream>>>(x, Wf1, dinv, A, N);
    gather128_k<true, _Float16><<<nb_node4, 256, 0, stream>>>(A, rowptr, eidx, dinv, b1, Ch, N);

    // ---- layer 2: HID=128 -> HID=128 ----
    gemm_ldsB_k<_Float16, 128, 128><<<nb_gemm, 256, 0, stream>>>(Ch, Wf2, dinv, A, N);
    gather128_k<true, _Float16><<<nb_node4, 256, 0, stream>>>(A, rowptr, eidx, dinv, b2, Ch, N);

    // ---- layer 3: HID=128 -> OUT=64 ----
    gemm_ldsB_k<_Float16, 128, 64><<<nb_gemm, 256, 0, stream>>>(Ch, Wf3, dinv, A, N);
    gather64_k<false><<<nb_node4, 256, 0, stream>>>(A, rowptr, eidx, dinv, b3, out, N);
}